// Round 13
// baseline (2994.148 us; speedup 1.0000x reference)
//
#include <hip/hip_runtime.h>
#include <cstddef>

#define S_LEN   4096
#define DMODEL  768
#define NHEAD   12
#define DHEAD   64
#define FDIM    3072
#define NLAYER  12
#define WIN     256
#define NGLOB   8
#define GSTRIDE 512

typedef short bf16x8 __attribute__((ext_vector_type(8)));
typedef float f32x4 __attribute__((ext_vector_type(4)));
typedef unsigned short u16;

__device__ __forceinline__ u16 f2bf(float f) {
  unsigned u = __builtin_bit_cast(unsigned, f);
  return (u16)((u + 0x7FFFu + ((u >> 16) & 1u)) >> 16);
}
__device__ __forceinline__ float bf2f(u16 s) {
  unsigned u = ((unsigned)s) << 16;
  return __builtin_bit_cast(float, u);
}

// async global->LDS, 16B per lane; lds base must be wave-uniform (HW adds lane*16)
__device__ __forceinline__ void gload16(const void* g, void* l) {
  __builtin_amdgcn_global_load_lds(
      (const __attribute__((address_space(1))) void*)g,
      (__attribute__((address_space(3))) void*)l, 16, 0, 0);
}

__device__ __forceinline__ float wave_sum(float v) {
#pragma unroll
  for (int off = 32; off > 0; off >>= 1) v += __shfl_xor(v, off);
  return v;
}

__device__ __forceinline__ float block_sum256(float v, float* sbuf) {
  v = wave_sum(v);
  int w = threadIdx.x >> 6;
  __syncthreads();
  if ((threadIdx.x & 63) == 0) sbuf[w] = v;
  __syncthreads();
  return sbuf[0] + sbuf[1] + sbuf[2] + sbuf[3];
}

// ---------------- embedding + LN (writes f32 h and bf16 hb) ----------------
__global__ __launch_bounds__(256) void embed_ln_kernel(
    const int* __restrict__ x, const float* __restrict__ wemb,
    const float* __restrict__ pemb, const float* __restrict__ gg,
    const float* __restrict__ bb, float* __restrict__ h, u16* __restrict__ hb) {
  __shared__ float sbuf[4];
  int s = blockIdx.x, tid = threadIdx.x;
  int idx = x[s];
  float vals[3];
#pragma unroll
  for (int i = 0; i < 3; i++) {
    int d = tid + i * 256;
    vals[i] = wemb[(size_t)idx * DMODEL + d] + pemb[(size_t)s * DMODEL + d];
  }
  float mean = block_sum256(vals[0] + vals[1] + vals[2], sbuf) * (1.0f / 768.0f);
  float sq = 0.f;
#pragma unroll
  for (int i = 0; i < 3; i++) { float t = vals[i] - mean; sq += t * t; }
  float inv = rsqrtf(block_sum256(sq, sbuf) * (1.0f / 768.0f) + 1e-5f);
#pragma unroll
  for (int i = 0; i < 3; i++) {
    int d = tid + i * 256;
    float r = (vals[i] - mean) * inv * gg[d] + bb[d];
    h[(size_t)s * DMODEL + d] = r;
    hb[(size_t)s * DMODEL + d] = f2bf(r);
  }
}

// ---------------- residual + LN (h f32 in-place; residual-delta r is bf16) --------
__global__ __launch_bounds__(256) void add_ln_kernel(
    float* __restrict__ h, const u16* __restrict__ r,
    const float* __restrict__ gg, const float* __restrict__ bb,
    u16* __restrict__ hb) {
  __shared__ float sbuf[4];
  int s = blockIdx.x, tid = threadIdx.x;
  float vals[3];
#pragma unroll
  for (int i = 0; i < 3; i++) {
    int d = tid + i * 256;
    vals[i] = h[(size_t)s * DMODEL + d] + bf2f(r[(size_t)s * DMODEL + d]);
  }
  float mean = block_sum256(vals[0] + vals[1] + vals[2], sbuf) * (1.0f / 768.0f);
  float sq = 0.f;
#pragma unroll
  for (int i = 0; i < 3; i++) { float t = vals[i] - mean; sq += t * t; }
  float inv = rsqrtf(block_sum256(sq, sbuf) * (1.0f / 768.0f) + 1e-5f);
#pragma unroll
  for (int i = 0; i < 3; i++) {
    int d = tid + i * 256;
    float rr = (vals[i] - mean) * inv * gg[d] + bb[d];
    h[(size_t)s * DMODEL + d] = rr;
    hb[(size_t)s * DMODEL + d] = f2bf(rr);
  }
}

// ---------------- ALL-layer weight convert+transpose: W[K][N] f32 -> Wt[N][K] bf16 ----
#define DD_ ((size_t)DMODEL * DMODEL)
#define DF_ ((size_t)DMODEL * FDIM)
#define WSTRIDE (6 * DD_ + 2 * DF_)
__global__ __launch_bounds__(256) void convw_kernel(
    const float* __restrict__ Wq, const float* __restrict__ Wk,
    const float* __restrict__ Wv, const float* __restrict__ Wkg,
    const float* __restrict__ Wvg, const float* __restrict__ Wo,
    const float* __restrict__ W1, const float* __restrict__ W2,
    u16* __restrict__ wt) {
  int l = blockIdx.y;
  int bid = blockIdx.x;
  const float* src; u16* dst; int K, N, r;
  u16* base = wt + (size_t)l * WSTRIDE;
  if (bid < 864) {
    int m = bid / 144; r = bid % 144; K = 768; N = 768;
    switch (m) {
      case 0: src = Wq  + l * DD_; dst = base;           break;
      case 1: src = Wk  + l * DD_; dst = base + 1 * DD_; break;
      case 2: src = Wv  + l * DD_; dst = base + 2 * DD_; break;
      case 3: src = Wkg + l * DD_; dst = base + 3 * DD_; break;
      case 4: src = Wvg + l * DD_; dst = base + 4 * DD_; break;
      default: src = Wo + l * DD_; dst = base + 5 * DD_; break;
    }
  } else if (bid < 1440) {
    r = bid - 864; K = 768; N = 3072; src = W1 + l * DF_; dst = base + 6 * DD_;
  } else {
    r = bid - 1440; K = 3072; N = 768; src = W2 + l * DF_; dst = base + 6 * DD_ + DF_;
  }
  int nt = N / 64;
  int tk = (r / nt) * 64, tn = (r % nt) * 64;
  int t = threadIdx.x;
  int c = t >> 2, ko = t & 3;
#pragma unroll
  for (int p = 0; p < 2; p++) {
    int kb = (p * 4 + ko) * 8;
    const float* sp = src + (size_t)(tk + kb) * N + tn + c;
    bf16x8 val;
#pragma unroll
    for (int j = 0; j < 8; j++) val[j] = (short)f2bf(sp[(size_t)j * N]);
    *(bf16x8*)&dst[(size_t)(tn + c) * K + tk + kb] = val;
  }
}

// ---------------- bf16 MFMA GEMM core (A bf16 [M][K], Wt bf16 [N][K]) ----------------
// TM x 128 tile, BK=64, 4 waves (2x2), 16x16x32 MFMA.  Single-buffered global_load_lds,
// linear LDS dest + inverse-swizzled global source; ds_read applies same XOR.
// OUTM==1 (bf16 row-major): operand-SWAPPED MFMA (bfr first) so each lane holds 4
// consecutive N-columns of one row -> packed ushort4 (8B) stores, float4 bias.
// OUTM==2 (bf16 transposed [N][M]): original order; lane holds 4 consecutive M-rows
// of one transposed row -> packed ushort4 stores too.
template <int ACT, int OUTM, int TM>
__device__ __forceinline__ void mm_core(const u16* __restrict__ A, const u16* __restrict__ Wt,
                                        const float* __restrict__ bias, void* __restrict__ Cv,
                                        int M, int N, int K, int bm, int bn,
                                        u16* As, u16* Bs) {
  constexpr int MR = TM / 32;
  constexpr int AJ = TM / 32;
  int t = threadIdx.x;
  int wid = t >> 6, lane = t & 63;
  int wr = (wid >> 1) * (TM / 2), wc = (wid & 1) * 64;
  int lr = lane & 15, lg = lane >> 4;
  f32x4 acc[MR][4];
  f32x4 zf = {0.f, 0.f, 0.f, 0.f};
#pragma unroll
  for (int m = 0; m < MR; m++)
#pragma unroll
    for (int n = 0; n < 4; n++) acc[m][n] = zf;

  int srow = wid * 8 + (lane >> 3);
  int sgr = (lane & 7) ^ (lane >> 3);
  const u16* aSrc = A + (size_t)(bm + srow) * K + sgr * 8;
  const u16* bSrc = Wt + (size_t)(bn + srow) * K + sgr * 8;
  int dstOff = wid * 8 * 64;

  for (int kt = 0; kt < K; kt += 64) {
    __syncthreads();
#pragma unroll
    for (int j = 0; j < AJ; j++)
      gload16(aSrc + kt + (size_t)j * 32 * K, As + dstOff + j * 32 * 64);
#pragma unroll
    for (int j = 0; j < 4; j++)
      gload16(bSrc + kt + (size_t)j * 32 * K, Bs + dstOff + j * 32 * 64);
    __syncthreads();
#pragma unroll
    for (int ks = 0; ks < 2; ks++) {
      bf16x8 af[MR], bfr[4];
#pragma unroll
      for (int m = 0; m < MR; m++)
        af[m] = *(const bf16x8*)&As[(wr + m * 16 + lr) * 64 + (((ks * 4 + lg) ^ (lr & 7)) * 8)];
#pragma unroll
      for (int n = 0; n < 4; n++)
        bfr[n] = *(const bf16x8*)&Bs[(wc + n * 16 + lr) * 64 + (((ks * 4 + lg) ^ (lr & 7)) * 8)];
#pragma unroll
      for (int m = 0; m < MR; m++)
#pragma unroll
        for (int n = 0; n < 4; n++) {
          if (OUTM == 1)
            acc[m][n] = __builtin_amdgcn_mfma_f32_16x16x32_bf16(bfr[n], af[m], acc[m][n], 0, 0, 0);
          else
            acc[m][n] = __builtin_amdgcn_mfma_f32_16x16x32_bf16(af[m], bfr[n], acc[m][n], 0, 0, 0);
        }
    }
  }
  if (OUTM == 1) {
    // swapped mapping: row = ... + lr  (A-side free idx in lane&15 slot),
    //                  col = ... + lg*4 + r (B-side free idx in reg slot)
#pragma unroll
    for (int m = 0; m < MR; m++) {
      int row = bm + wr + m * 16 + lr;
#pragma unroll
      for (int n = 0; n < 4; n++) {
        int col0 = bn + wc + n * 16 + lg * 4;
        float4 bb4 = *(const float4*)&bias[col0];
        float bv[4] = {bb4.x, bb4.y, bb4.z, bb4.w};
        ushort4 outv;
        u16 tv[4];
#pragma unroll
        for (int r = 0; r < 4; r++) {
          float xv = acc[m][n][r] + bv[r];
          if (ACT == 1) xv = 0.5f * xv * (1.0f + erff(xv * 0.70710678118654752f));
          tv[r] = f2bf(xv);
        }
        outv.x = tv[0]; outv.y = tv[1]; outv.z = tv[2]; outv.w = tv[3];
        *(ushort4*)&((u16*)Cv)[(size_t)row * N + col0] = outv;
      }
    }
  } else {
    // original mapping: col = ... + lr, row = ... + lg*4 + r; transposed store
    // dst[(col)*M + row0..row0+3] is contiguous -> ushort4.
#pragma unroll
    for (int n = 0; n < 4; n++) {
      int col = bn + wc + n * 16 + lr;
      float bb = bias[col];
#pragma unroll
      for (int m = 0; m < MR; m++) {
        int row0 = bm + wr + m * 16 + lg * 4;
        ushort4 outv;
        u16 tv[4];
#pragma unroll
        for (int r = 0; r < 4; r++) {
          float xv = acc[m][n][r] + bb;
          if (ACT == 1) xv = 0.5f * xv * (1.0f + erff(xv * 0.70710678118654752f));
          tv[r] = f2bf(xv);
        }
        outv.x = tv[0]; outv.y = tv[1]; outv.z = tv[2]; outv.w = tv[3];
        *(ushort4*)&((u16*)Cv)[(size_t)col * M + row0] = outv;
      }
    }
  }
}

// XCD-aware bijective swizzle (nwg % 8 == 0): chunk of nwg/8 consecutive logical
// blocks per XCD; logical order is bx-major so each XCD's B-panels stay L2-resident.
template <int ACT, int OUTM, int TM>
__global__ __launch_bounds__(256) void mm_kernel(const u16* A, const u16* Wt, const float* bias,
                                                 void* Cv, int M, int N, int K) {
  __shared__ u16 As[TM * 64];
  __shared__ u16 Bs[128 * 64];
  int nwg = gridDim.x * gridDim.y;
  int lin = blockIdx.y * gridDim.x + blockIdx.x;
  int swz = (lin & 7) * (nwg >> 3) + (lin >> 3);
  int bx = swz / gridDim.y, by = swz % gridDim.y;
  mm_core<ACT, OUTM, TM>(A, Wt, bias, Cv, M, N, K, by * TM, bx * 128, As, Bs);
}

// fused q/k/v/kg/vg projections (+ qg projection on the extra x-slot).
// slots 2 (v) and 4 (vg) store transposed.
__global__ __launch_bounds__(256) void mm5_kernel(
    const u16* A,
    const u16* W0, const u16* W1_, const u16* W2_, const u16* W3, const u16* W4,
    const float* b0, const float* b1, const float* b2, const float* b3, const float* b4,
    u16* C0, u16* C1, u16* C2, u16* C3, u16* C4, int M, int K,
    const float* __restrict__ h, const float* __restrict__ Wqg,
    const float* __restrict__ bqg, float* __restrict__ qg) {
  __shared__ u16 As[128 * 64];
  __shared__ u16 Bs[128 * 64];
  if (blockIdx.x == 30) {        // qg projection: 24 used blocks (8 gi x 3 col-blocks)
    int b = blockIdx.y;
    if (b >= 24) return;
    int gi = b / 3, c0 = (b % 3) * 256;
    int tid = threadIdx.x;
    float* hs = (float*)As;
    const float* hrow = h + (size_t)gi * GSTRIDE * DMODEL;
    for (int i = tid; i < DMODEL; i += 256) hs[i] = hrow[i];
    __syncthreads();
    float a = bqg[c0 + tid];
    for (int k = 0; k < DMODEL; k++) a += hs[k] * Wqg[(size_t)k * DMODEL + c0 + tid];
    qg[gi * DMODEL + c0 + tid] = a;
    return;
  }
  // 960 GEMM blocks: XCD swizzle, bx-major logical order (~4 B-panels per XCD chunk)
  int lin = blockIdx.y * 30 + blockIdx.x;
  int swz = (lin & 7) * 120 + (lin >> 3);
  int bx = swz >> 5, by = swz & 31;
  int which = bx / 6;
  int bn = (bx % 6) * 128;
  const u16* Ws[5] = {W0, W1_, W2_, W3, W4};
  const float* bs[5] = {b0, b1, b2, b3, b4};
  u16* Cs[5] = {C0, C1, C2, C3, C4};
  if (which == 2 || which == 4)
    mm_core<0, 2, 128>(A, Ws[which], bs[which], Cs[which], M, DMODEL, K, by * 128, bn, As, Bs);
  else
    mm_core<0, 1, 128>(A, Ws[which], bs[which], Cs[which], M, DMODEL, K, by * 128, bn, As, Bs);
}

// ---------------- sliding-window flash attention body (MFMA, 128-query tiles) ------
// Softmax: defer-max (T13) + deferred l-partials: common path has NO shuffle trees
// (local col-max + __any gate; per-lane partial sums, one butterfly at the end).
__device__ __forceinline__ void sliding_body(
    int bid, u16* Ps,
    const u16* __restrict__ qb, const u16* __restrict__ kb,
    const u16* __restrict__ vt, const int* __restrict__ xmask,
    u16* __restrict__ ctx) {
  int hh = bid >> 5;
  int q0 = (bid & 31) * 128;
  int w = threadIdx.x >> 6, lane = threadIdx.x & 63;
  int lr = lane & 15, lg = lane >> 4;
  int rowb = q0 + w * 32;
  f32x4 zf = {0.f, 0.f, 0.f, 0.f};
  u16* Pw = Ps + w * 2048;

  bf16x8 qf[2][2];
#pragma unroll
  for (int mf = 0; mf < 2; mf++) {
    const u16* qptr = qb + (size_t)(rowb + mf * 16 + lr) * DMODEL + hh * DHEAD;
    qf[mf][0] = *(const bf16x8*)(qptr + lg * 8);
    qf[mf][1] = *(const bf16x8*)(qptr + 32 + lg * 8);
  }

  float m_run[2][4], l_run[2][4];   // m row-uniform; l per-lane partial
  f32x4 ctxa[2][4];
#pragma unroll
  for (int mf = 0; mf < 2; mf++)
#pragma unroll
    for (int r = 0; r < 4; r++) {
      m_run[mf][r] = -1e30f; l_run[mf][r] = 0.f; ctxa[mf][r] = zf;
    }

  // ---- global-key tile (8 keys; P cols 0..15 real, 16..31 zeroed for PV) ----
  {
    int krow = (lr < NGLOB) ? lr * GSTRIDE : 0;
    const u16* kp = kb + (size_t)krow * DMODEL + hh * DHEAD + lg * 8;
    bf16x8 kf0 = *(const bf16x8*)kp;
    bf16x8 kf1 = *(const bf16x8*)(kp + 32);
#pragma unroll
    for (int mf = 0; mf < 2; mf++) {
      f32x4 sa = __builtin_amdgcn_mfma_f32_16x16x32_bf16(qf[mf][0], kf0, zf, 0, 0, 0);
      sa = __builtin_amdgcn_mfma_f32_16x16x32_bf16(qf[mf][1], kf1, sa, 0, 0, 0);
      float p0[4], tmax[4];
#pragma unroll
      for (int r = 0; r < 4; r++) {
        float s = (lr < NGLOB) ? sa[r] * 0.125f : -1e30f;
        p0[r] = s; tmax[r] = s;
      }
#pragma unroll
      for (int o = 8; o; o >>= 1)
#pragma unroll
        for (int r = 0; r < 4; r++) tmax[r] = fmaxf(tmax[r], __shfl_xor(tmax[r], o));
#pragma unroll
      for (int r = 0; r < 4; r++) {
        m_run[mf][r] = tmax[r];           // finite: global keys always valid
        p0[r] = __expf(p0[r] - tmax[r]);  // masked lanes -> exp(-huge) = 0
        l_run[mf][r] = p0[r];             // per-lane partial (own column)
      }
#pragma unroll
      for (int r = 0; r < 4; r++) {
        int qi = mf * 16 + lg * 4 + r;
        Pw[qi * 64 + (((lr >> 3) ^ (qi & 7)) * 8) + (lr & 7)] = f2bf(p0[r]);
        int k2 = 16 + lr;
        Pw[qi * 64 + (((k2 >> 3) ^ (qi & 7)) * 8) + (k2 & 7)] = 0;
      }
    }
    bf16x8 pf0 = *(const bf16x8*)&Pw[lr * 64 + ((lg ^ (lr & 7)) * 8)];
    bf16x8 pf1 = *(const bf16x8*)&Pw[(16 + lr) * 64 + ((lg ^ (lr & 7)) * 8)];
#pragma unroll
    for (int c2 = 0; c2 < 4; c2++) {
      bf16x8 vg8 = {0, 0, 0, 0, 0, 0, 0, 0};
      if (lg == 0) {
        const u16* vrow = vt + (size_t)(hh * DHEAD + c2 * 16 + lr) * S_LEN;
#pragma unroll
        for (int j = 0; j < 8; j++) vg8[j] = (short)vrow[(size_t)j * GSTRIDE];
      }
      ctxa[0][c2] = __builtin_amdgcn_mfma_f32_16x16x32_bf16(pf0, vg8, ctxa[0][c2], 0, 0, 0);
      ctxa[1][c2] = __builtin_amdgcn_mfma_f32_16x16x32_bf16(pf1, vg8, ctxa[1][c2], 0, 0, 0);
    }
  }

  // ---- 10 band tiles of 64 keys, covering [q0-256, q0+383] ----
  for (int tt = 0; tt < 10; tt++) {
    int base = q0 - WIN + tt * 64;
    if (base + 63 < 0 || base >= S_LEN) continue;
    bf16x8 kf[4][2];
    int keyc[4]; bool vc[4];
#pragma unroll
    for (int c = 0; c < 4; c++) {
      int key = base + c * 16 + lr;
      int krow = key < 0 ? 0 : (key > S_LEN - 1 ? S_LEN - 1 : key);
      vc[c] = (key >= 0) && (key < S_LEN) && ((key & (GSTRIDE - 1)) != 0) && (xmask[krow] != 0);
      keyc[c] = key;
      const u16* kp = kb + (size_t)krow * DMODEL + hh * DHEAD + lg * 8;
      kf[c][0] = *(const bf16x8*)kp;
      kf[c][1] = *(const bf16x8*)(kp + 32);
    }
#pragma unroll
    for (int mf = 0; mf < 2; mf++) {
      f32x4 sa[4];
#pragma unroll
      for (int c = 0; c < 4; c++) {
        sa[c] = __builtin_amdgcn_mfma_f32_16x16x32_bf16(qf[mf][0], kf[c][0], zf, 0, 0, 0);
        sa[c] = __builtin_amdgcn_mfma_f32_16x16x32_bf16(qf[mf][1], kf[c][1], sa[c], 0, 0, 0);
      }
      float p[4][4], lmax[4] = {-1e30f, -1e30f, -1e30f, -1e30f};
#pragma unroll
      for (int c = 0; c < 4; c++)
#pragma unroll
        for (int r = 0; r < 4; r++) {
          int qrow = rowb + mf * 16 + lg * 4 + r;
          int dd = keyc[c] - qrow;
          float s = (vc[c] && dd >= -WIN && dd <= WIN) ? sa[c][r] * 0.125f : -1e30f;
          p[c][r] = s;
          lmax[r] = fmaxf(lmax[r], s);
        }
      // defer-max gate: no shuffle tree unless some lane exceeds m_run+8
      float need = 0.f;
#pragma unroll
      for (int r = 0; r < 4; r++) need = fmaxf(need, lmax[r] - m_run[mf][r]);
      if (__any(need > 8.f)) {
        float tmax[4];
#pragma unroll
        for (int r = 0; r < 4; r++) tmax[r] = lmax[r];
#pragma unroll
        for (int o = 8; o; o >>= 1)
#pragma unroll
          for (int r = 0; r < 4; r++) tmax[r] = fmaxf(tmax[r], __shfl_xor(tmax[r], o));
        float sc[4];
#pragma unroll
        for (int r = 0; r < 4; r++) {
          float mn = fmaxf(m_run[mf][r], tmax[r]);
          sc[r] = __expf(m_run[mf][r] - mn);
          m_run[mf][r] = mn;
          l_run[mf][r] *= sc[r];
        }
#pragma unroll
        for (int c2 = 0; c2 < 4; c2++)
#pragma unroll
          for (int r = 0; r < 4; r++) ctxa[mf][c2][r] *= sc[r];
      }
#pragma unroll
      for (int c = 0; c < 4; c++)
#pragma unroll
        for (int r = 0; r < 4; r++) {
          p[c][r] = __expf(p[c][r] - m_run[mf][r]);  // masked -> exp(-huge)=0 (m finite)
          l_run[mf][r] += p[c][r];
        }
#pragma unroll
      for (int c = 0; c < 4; c++)
#pragma unroll
        for (int r = 0; r < 4; r++) {
          int qi = mf * 16 + lg * 4 + r, k64 = c * 16 + lr;
          Pw[qi * 64 + (((k64 >> 3) ^ (qi & 7)) * 8) + (k64 & 7)] = f2bf(p[c][r]);
        }
    }
#pragma unroll
    for (int ks = 0; ks < 2; ks++) {
      bf16x8 pf0 = *(const bf16x8*)&Pw[lr * 64 + (((ks * 4 + lg) ^ (lr & 7)) * 8)];
      bf16x8 pf1 = *(const bf16x8*)&Pw[(16 + lr) * 64 + (((ks * 4 + lg) ^ (lr & 7)) * 8)];
      int kstart = base + ks * 32 + lg * 8;
      int kc = kstart < 0 ? 0 : (kstart > S_LEN - 8 ? S_LEN - 8 : kstart);
#pragma unroll
      for (int c2 = 0; c2 < 4; c2++) {
        const u16* vp = vt + (size_t)(hh * DHEAD + c2 * 16 + lr) * S_LEN + kc;
        bf16x8 vf = *(const bf16x8*)vp;
        ctxa[0][c2] = __builtin_amdgcn_mfma_f32_16x16x32_bf16(pf0, vf, ctxa[0][c2], 0, 0, 0);
        ctxa[1][c2] = __builtin_amdgcn_mfma_f32_16x16x32_bf16(pf1, vf, ctxa[1][c2], 0, 0, 0);
      }
    }
  }

  // finalize l: one butterfly over the 16-lane row group
#pragma unroll
  for (int mf = 0; mf < 2; mf++)
#pragma unroll
    for (int o = 8; o; o >>= 1)
#pragma unroll
      for (int r = 0; r < 4; r++) l_run[mf][r] += __shfl_xor(l_run[mf][r], o);

  // store (skip gpos rows — owned by the gattn blocks in this same dispatch)
#pragma unroll
  for (int mf = 0; mf < 2; mf++)
#pragma unroll
    for (int c2 = 0; c2 < 4; c2++)
#pragma unroll
      for (int r = 0; r < 4; r++) {
        int qrow = rowb + mf * 16 + lg * 4 + r;
        if ((qrow & (GSTRIDE - 1)) != 0)
          ctx[(size_t)qrow * DMODEL + hh * DHEAD + c2 * 16 + lr] = f2bf(ctxa[mf][c2][r] / l_run[mf][r]);
      }
}

// ---------------- single-pass global-token attention (one block per head) ---------
__device__ __forceinline__ void gattn_body(
    int hh, u16* Ps, float* cM, float* cL, float* cA,
    const float* __restrict__ qg, const u16* __restrict__ kg,
    const u16* __restrict__ vgt, const int* __restrict__ xmask,
    u16* __restrict__ ctx) {
  int w = threadIdx.x >> 6, lane = threadIdx.x & 63;
  int lr = lane & 15, lg = lane >> 4;
  f32x4 zf = {0.f, 0.f, 0.f, 0.f};
  u16* Pw = Ps + w * 1024;

  bf16x8 qf0, qf1;
  {
    const float* qp = qg + (size_t)(lr & 7) * DMODEL + hh * DHEAD;
    bool real = lr < 8;
#pragma unroll
    for (int j = 0; j < 8; j++) {
      qf0[j] = real ? (short)f2bf(0.125f * qp[lg * 8 + j]) : (short)0;
      qf1[j] = real ? (short)f2bf(0.125f * qp[32 + lg * 8 + j]) : (short)0;
    }
  }

  float m_run[4] = {-1e30f, -1e30f, -1e30f, -1e30f};
  float l_run[4] = {0.f, 0.f, 0.f, 0.f};    // per-lane partial
  f32x4 ctxa[4] = {zf, zf, zf, zf};

  for (int tt = w; tt < 64; tt += 4) {
    int base = tt * 64;
    f32x4 sa[4];
    bool vc[4];
#pragma unroll
    for (int st = 0; st < 4; st++) {
      int key = base + st * 16 + lr;
      vc[st] = (xmask[key] != 0) || ((key & (GSTRIDE - 1)) == 0);
      const u16* kp = kg + (size_t)key * DMODEL + hh * DHEAD + lg * 8;
      sa[st] = __builtin_amdgcn_mfma_f32_16x16x32_bf16(qf0, *(const bf16x8*)kp, zf, 0, 0, 0);
      sa[st] = __builtin_amdgcn_mfma_f32_16x16x32_bf16(qf1, *(const bf16x8*)(kp + 32), sa[st], 0, 0, 0);
    }
    float p[4][4], lmax[4] = {-1e30f, -1e30f, -1e30f, -1e30f};
#pragma unroll
    for (int st = 0; st < 4; st++)
#pragma unroll
      for (int r = 0; r < 4; r++) {
        float s = vc[st] ? sa[st][r] : -1e30f;
        p[st][r] = s;
        lmax[r] = fmaxf(lmax[r], s);
      }
    float need = 0.f;
#pragma unroll
    for (int r = 0; r < 4; r++) need = fmaxf(need, lmax[r] - m_run[r]);
    if (__any(need > 8.f)) {
      float tmax[4];
#pragma unroll
      for (int r = 0; r < 4; r++) tmax[r] = lmax[r];
#pragma unroll
      for (int o = 8; o; o >>= 1)
#pragma unroll
        for (int r = 0; r < 4; r++) tmax[r] = fmaxf(tmax[r], __shfl_xor(tmax[r], o));
      float sc[4];
#pragma unroll
      for (int r = 0; r < 4; r++) {
        float mn = fmaxf(m_run[r], tmax[r]);
        sc[r] = __expf(m_run[r] - mn);
        m_run[r] = mn;
        l_run[r] *= sc[r];
      }
#pragma unroll
      for (int c2 = 0; c2 < 4; c2++)
#pragma unroll
        for (int r = 0; r < 4; r++) ctxa[c2][r] *= sc[r];
    }
#pragma unroll
    for (int st = 0; st < 4; st++)
#pragma unroll
      for (int r = 0; r < 4; r++) {
        float pv = vc[st] ? __expf(p[st][r] - m_run[r]) : 0.f;  // guard: m may be -1e30
        p[st][r] = pv;
        l_run[r] += pv;
      }
#pragma unroll
    for (int st = 0; st < 4; st++)
#pragma unroll
      for (int r = 0; r < 4; r++) {
        int qi = lg * 4 + r, k64 = st * 16 + lr;
        Pw[qi * 64 + (((k64 >> 3) ^ (qi & 7)) * 8) + (k64 & 7)] = f2bf(p[st][r]);
      }
#pragma unroll
    for (int ks = 0; ks < 2; ks++) {
      bf16x8 pf = *(const bf16x8*)&Pw[lr * 64 + (((ks * 4 + lg) ^ (lr & 7)) * 8)];
      int kstart = base + ks * 32 + lg * 8;
#pragma unroll
      for (int c2 = 0; c2 < 4; c2++) {
        const u16* vp = vgt + (size_t)(hh * DHEAD + c2 * 16 + lr) * S_LEN + kstart;
        ctxa[c2] = __builtin_amdgcn_mfma_f32_16x16x32_bf16(pf, *(const bf16x8*)vp, ctxa[c2], 0, 0, 0);
      }
    }
  }

  // finalize per-wave l (butterfly), then write partials for 4-way combine
#pragma unroll
  for (int o = 8; o; o >>= 1)
#pragma unroll
    for (int r = 0; r < 4; r++) l_run[r] += __shfl_xor(l_run[r], o);

  if (lg < 2) {
#pragma unroll
    for (int r = 0; r < 4; r++) {
      int q = lg * 4 + r;
#pragma unroll
      for (int c2 = 0; c2 < 4; c2++)
        cA[(w * 8 + q) * 64 + c2 * 16 + lr] = ctxa[c2][r];
      if (lr == 0) {
        cM[w * 8 + q] = m_run[r];
        cL[w * 8 + q] = l_run[r];
      }
    }
  }
  __syncthreads();
  int t = threadIdx.x;
#pragma unroll
  for (int half = 0; half < 2; half++) {
    int slot = half * 256 + t;      // q*64 + d
    int q = slot >> 6, d = slot & 63;
    float M = fmaxf(fmaxf(cM[q], cM[8 + q]), fmaxf(cM[16 + q], cM[24 + q]));
    float L = 0.f, A = 0.f;
#pragma unroll
    for (int ww = 0; ww < 4; ww++) {
      float al = __expf(cM[ww * 8 + q] - M);
      L += cL[ww * 8 + q] * al;
      A += cA[(ww * 8 + q) * 64 + d] * al;
    }
    ctx[(size_t)q * GSTRIDE * DMODEL + hh * DHEAD + d] = f2bf(A / L);
  }
}

// ---------------- merged attention dispatch: gattn (12) + sliding (384) ----------
__global__ __launch_bounds__(256) void attn_kernel(
    const u16* __restrict__ qb, const u16* __restrict__ kb,
    const u16* __restrict__ vt, const int* __restrict__ xmask,
    u16* __restrict__ ctx,
    const float* __restrict__ qg, const u16* __restrict__ kg,
    const u16* __restrict__ vgt) {
  __shared__ u16 Ps[4 * 32 * 64];
  __shared__ float cM[32], cL[32], cA[32 * 64];
  int bid = blockIdx.x;
  if (bid < NHEAD) {
    gattn_body(bid, Ps, cM, cL, cA, qg, kg, vgt, xmask, ctx);
  } else {
    sliding_body(bid - NHEAD, Ps, qb, kb, vt, xmask, ctx);
  }
}

// ---------------- CLS pooling + output projection -----------------
__global__ __launch_bounds__(128) void cls_out_kernel(
    const float* __restrict__ h, const float* __restrict__ ow,
    const float* __restrict__ ob, float* __restrict__ y) {
  __shared__ float hs[DMODEL];
  int wi = blockIdx.x;
  int tid = threadIdx.x;
  for (int i = tid; i < DMODEL; i += 128) hs[i] = h[(size_t)wi * GSTRIDE * DMODEL + i];
  __syncthreads();
  float a = ob[tid];
  for (int d = 0; d < DMODEL; d++) a += hs[d] * ow[d * 128 + tid];
  y[wi * 128 + tid] = a;
}

// ---------------- host launch ----------------
extern "C" void kernel_launch(void* const* d_in, const int* in_sizes, int n_in,
                              void* d_out, int out_size, void* d_ws, size_t ws_size,
                              hipStream_t stream) {
  const int*   x      = (const int*)d_in[0];
  const int*   xmask  = (const int*)d_in[1];
  const float* wemb   = (const float*)d_in[2];
  const float* pemb   = (const float*)d_in[3];
  const float* emb_g  = (const float*)d_in[4];
  const float* emb_b  = (const float*)d_in[5];
  const float* Wq     = (const float*)d_in[6];
  const float* bq     = (const float*)d_in[7];
  const float* Wk     = (const float*)d_in[8];
  const float* bk     = (const float*)d_in[9];
  const float* Wv     = (const float*)d_in[10];
  const float* bv     = (const float*)d_in[11];
  const float* Wo     = (const float*)d_in[12];
  const float* bo     = (const float*)d_in[13];
  const float* Wqg    = (const float*)d_in[14];
  const float* bqg    = (const float*)d_in[15];
  const float* Wkg    = (const float*)d_in[16];
  const float* bkg    = (const float*)d_in[17];
  const float* Wvg    = (const float*)d_in[18];
  const float* bvg    = (const float*)d_in[19];
  const float* ln1_g  = (const float*)d_in[20];
  const float* ln1_b  = (const float*)d_in[21];
  const float* W1     = (const float*)d_in[22];
  const float* b1     = (const float*)d_in[23];
  const float* W2     = (const float*)d_in[24];
  const float* b2     = (const float*)d_in[25];
  const float* ln2_g  = (const float*)d_in[26];
  const float* ln2_b  = (const float*)d_in[27];
  const float* out_w  = (const float*)d_in[28];
  const float* out_b  = (const float*)d_in[29];

  char* wsp = (char*)d_ws;
  float* h   = (float*)wsp;  wsp += (size_t)S_LEN * DMODEL * 4;
  u16* tmpb  = (u16*)wsp;    wsp += (size_t)S_LEN * DMODEL * 2;
  u16* hb  = (u16*)wsp;      wsp += (size_t)S_LEN * DMODEL * 2;
  u16* ctx = (u16*)wsp;      wsp += (size_t)S_LEN * DMODEL * 2;
  u16* qb  = (u16*)wsp;      wsp += (size_t)S_LEN * DMODEL * 2;
  u16* kb  = (u16*)wsp;      wsp += (size_t)S_LEN * DMODEL * 2;
  u16* vt  = (u16*)wsp;      wsp += (size_t)S_LEN * DMODEL * 2;
  u16* kgb = (u16*)wsp;      wsp += (size_t)S_LEN * DMODEL * 2;
  u16* vgt = (u16*)wsp;      wsp += (size_t)S_LEN * DMODEL * 2;
  u16* mid = (u16*)wsp;      wsp += (size_t)S_LEN * FDIM * 2;
  float* qgb = (float*)wsp;  wsp += (size_t)NGLOB * DMODEL * 4;
  u16* wtb = (u16*)wsp;      wsp += WSTRIDE * NLAYER * 2;

  embed_ln_kernel<<<S_LEN, 256, 0, stream>>>(x, wemb, pemb, emb_g, emb_b, h, hb);
  convw_kernel<<<dim3(2016, NLAYER), 256, 0, stream>>>(Wq, Wk, Wv, Wkg, Wvg, Wo, W1, W2, wtb);

  for (int l = 0; l < NLAYER; l++) {
    const float* bql  = bq  + (size_t)l * DMODEL;
    const float* bkl  = bk  + (size_t)l * DMODEL;
    const float* bvl  = bv  + (size_t)l * DMODEL;
    const float* bol  = bo  + (size_t)l * DMODEL;
    const float* wqg  = Wqg + (size_t)l * DD_;
    const float* bqgl = bqg + (size_t)l * DMODEL;
    const float* bkgl = bkg + (size_t)l * DMODEL;
    const float* bvgl = bvg + (size_t)l * DMODEL;
    const float* b1l  = b1  + (size_t)l * FDIM;
    const float* b2l  = b2  + (size_t)l * DMODEL;
    u16* base = wtb + (size_t)l * WSTRIDE;
    u16* wqT  = base;
    u16* wkT  = base + 1 * DD_;
    u16* wvT  = base + 2 * DD_;
    u16* wkgT = base + 3 * DD_;
    u16* wvgT = base + 4 * DD_;
    u16* woT  = base + 5 * DD_;
    u16* w1T  = base + 6 * DD_;
    u16* w2T  = base + 6 * DD_ + DF_;

    mm5_kernel<<<dim3(31, 32), 256, 0, stream>>>(
        hb, wqT, wkT, wvT, wkgT, wvgT, bql, bkl, bvl, bkgl, bvgl,
        qb, kb, vt, kgb, vgt, S_LEN, DMODEL, h, wqg, bqgl, qgb);

    attn_kernel<<<NHEAD + NHEAD * 32, 256, 0, stream>>>(
        qb, kb, vt, xmask, ctx, qgb, kgb, vgt);

    mm_kernel<0, 1, 64><<<dim3(6, 64), 256, 0, stream>>>(ctx, woT, bol, tmpb, S_LEN, DMODEL, DMODEL);
    add_ln_kernel<<<S_LEN, 256, 0, stream>>>(h, tmpb, ln1_g + (size_t)l * DMODEL,
                                             ln1_b + (size_t)l * DMODEL, hb);

    mm_kernel<1, 1, 128><<<dim3(24, 32), 256, 0, stream>>>(hb, w1T, b1l, mid, S_LEN, FDIM, DMODEL);
    mm_kernel<0, 1, 64><<<dim3(6, 64), 256, 0, stream>>>(mid, w2T, b2l, tmpb, S_LEN, DMODEL, FDIM);
    add_ln_kernel<<<S_LEN, 256, 0, stream>>>(h, tmpb, ln2_g + (size_t)l * DMODEL,
                                             ln2_b + (size_t)l * DMODEL, hb);
  }

  cls_out_kernel<<<NGLOB, 128, 0, stream>>>(h, out_w, out_b, (float*)d_out);
}

// Round 14
// 2924.302 us; speedup vs baseline: 1.0239x; 1.0239x over previous
//
#include <hip/hip_runtime.h>
#include <cstddef>

#define S_LEN   4096
#define DMODEL  768
#define NHEAD   12
#define DHEAD   64
#define FDIM    3072
#define NLAYER  12
#define WIN     256
#define NGLOB   8
#define GSTRIDE 512

typedef short bf16x8 __attribute__((ext_vector_type(8)));
typedef float f32x4 __attribute__((ext_vector_type(4)));
typedef unsigned short u16;

__device__ __forceinline__ u16 f2bf(float f) {
  unsigned u = __builtin_bit_cast(unsigned, f);
  return (u16)((u + 0x7FFFu + ((u >> 16) & 1u)) >> 16);
}
__device__ __forceinline__ float bf2f(u16 s) {
  unsigned u = ((unsigned)s) << 16;
  return __builtin_bit_cast(float, u);
}

// async global->LDS, 16B per lane; lds base must be wave-uniform (HW adds lane*16)
__device__ __forceinline__ void gload16(const void* g, void* l) {
  __builtin_amdgcn_global_load_lds(
      (const __attribute__((address_space(1))) void*)g,
      (__attribute__((address_space(3))) void*)l, 16, 0, 0);
}

__device__ __forceinline__ float wave_sum(float v) {
#pragma unroll
  for (int off = 32; off > 0; off >>= 1) v += __shfl_xor(v, off);
  return v;
}

__device__ __forceinline__ float block_sum256(float v, float* sbuf) {
  v = wave_sum(v);
  int w = threadIdx.x >> 6;
  __syncthreads();
  if ((threadIdx.x & 63) == 0) sbuf[w] = v;
  __syncthreads();
  return sbuf[0] + sbuf[1] + sbuf[2] + sbuf[3];
}

// ---------------- embedding + LN (writes f32 h and bf16 hb) ----------------
__global__ __launch_bounds__(256) void embed_ln_kernel(
    const int* __restrict__ x, const float* __restrict__ wemb,
    const float* __restrict__ pemb, const float* __restrict__ gg,
    const float* __restrict__ bb, float* __restrict__ h, u16* __restrict__ hb) {
  __shared__ float sbuf[4];
  int s = blockIdx.x, tid = threadIdx.x;
  int idx = x[s];
  float vals[3];
#pragma unroll
  for (int i = 0; i < 3; i++) {
    int d = tid + i * 256;
    vals[i] = wemb[(size_t)idx * DMODEL + d] + pemb[(size_t)s * DMODEL + d];
  }
  float mean = block_sum256(vals[0] + vals[1] + vals[2], sbuf) * (1.0f / 768.0f);
  float sq = 0.f;
#pragma unroll
  for (int i = 0; i < 3; i++) { float t = vals[i] - mean; sq += t * t; }
  float inv = rsqrtf(block_sum256(sq, sbuf) * (1.0f / 768.0f) + 1e-5f);
#pragma unroll
  for (int i = 0; i < 3; i++) {
    int d = tid + i * 256;
    float r = (vals[i] - mean) * inv * gg[d] + bb[d];
    h[(size_t)s * DMODEL + d] = r;
    hb[(size_t)s * DMODEL + d] = f2bf(r);
  }
}

// ---------------- residual + LN (h f32 in-place; residual-delta r is bf16) --------
__global__ __launch_bounds__(256) void add_ln_kernel(
    float* __restrict__ h, const u16* __restrict__ r,
    const float* __restrict__ gg, const float* __restrict__ bb,
    u16* __restrict__ hb) {
  __shared__ float sbuf[4];
  int s = blockIdx.x, tid = threadIdx.x;
  float vals[3];
#pragma unroll
  for (int i = 0; i < 3; i++) {
    int d = tid + i * 256;
    vals[i] = h[(size_t)s * DMODEL + d] + bf2f(r[(size_t)s * DMODEL + d]);
  }
  float mean = block_sum256(vals[0] + vals[1] + vals[2], sbuf) * (1.0f / 768.0f);
  float sq = 0.f;
#pragma unroll
  for (int i = 0; i < 3; i++) { float t = vals[i] - mean; sq += t * t; }
  float inv = rsqrtf(block_sum256(sq, sbuf) * (1.0f / 768.0f) + 1e-5f);
#pragma unroll
  for (int i = 0; i < 3; i++) {
    int d = tid + i * 256;
    float rr = (vals[i] - mean) * inv * gg[d] + bb[d];
    h[(size_t)s * DMODEL + d] = rr;
    hb[(size_t)s * DMODEL + d] = f2bf(rr);
  }
}

// ---------------- ALL-layer weight convert+transpose: W[K][N] f32 -> Wt[N][K] bf16 ----
#define DD_ ((size_t)DMODEL * DMODEL)
#define DF_ ((size_t)DMODEL * FDIM)
#define WSTRIDE (6 * DD_ + 2 * DF_)
__global__ __launch_bounds__(256) void convw_kernel(
    const float* __restrict__ Wq, const float* __restrict__ Wk,
    const float* __restrict__ Wv, const float* __restrict__ Wkg,
    const float* __restrict__ Wvg, const float* __restrict__ Wo,
    const float* __restrict__ W1, const float* __restrict__ W2,
    u16* __restrict__ wt) {
  int l = blockIdx.y;
  int bid = blockIdx.x;
  const float* src; u16* dst; int K, N, r;
  u16* base = wt + (size_t)l * WSTRIDE;
  if (bid < 864) {
    int m = bid / 144; r = bid % 144; K = 768; N = 768;
    switch (m) {
      case 0: src = Wq  + l * DD_; dst = base;           break;
      case 1: src = Wk  + l * DD_; dst = base + 1 * DD_; break;
      case 2: src = Wv  + l * DD_; dst = base + 2 * DD_; break;
      case 3: src = Wkg + l * DD_; dst = base + 3 * DD_; break;
      case 4: src = Wvg + l * DD_; dst = base + 4 * DD_; break;
      default: src = Wo + l * DD_; dst = base + 5 * DD_; break;
    }
  } else if (bid < 1440) {
    r = bid - 864; K = 768; N = 3072; src = W1 + l * DF_; dst = base + 6 * DD_;
  } else {
    r = bid - 1440; K = 3072; N = 768; src = W2 + l * DF_; dst = base + 6 * DD_ + DF_;
  }
  int nt = N / 64;
  int tk = (r / nt) * 64, tn = (r % nt) * 64;
  int t = threadIdx.x;
  int c = t >> 2, ko = t & 3;
#pragma unroll
  for (int p = 0; p < 2; p++) {
    int kb = (p * 4 + ko) * 8;
    const float* sp = src + (size_t)(tk + kb) * N + tn + c;
    bf16x8 val;
#pragma unroll
    for (int j = 0; j < 8; j++) val[j] = (short)f2bf(sp[(size_t)j * N]);
    *(bf16x8*)&dst[(size_t)(tn + c) * K + tk + kb] = val;
  }
}

// ---------------- bf16 MFMA GEMM core (A bf16 [M][K], Wt bf16 [N][K]) ----------------
// TM x 128 tile, BK=64, 4 waves (2x2), 16x16x32 MFMA.  Single-buffered global_load_lds,
// linear LDS dest + inverse-swizzled global source; ds_read applies same XOR.
// (r10: BK=32 2-phase lost 5% — doubled barrier drains; r6: BK=64 dbuf lost — halved
//  occupancy; r13: swapped-operand packed epilogue lost 2% — stores already hidden.
//  This 1-phase BK=64 + ~5 blocks/CU TLP + scalar epilogue is the measured optimum.)
template <int ACT, int OUTM, int TM>  // OUTM: 0=f32 rm, 1=bf16 rm, 2=bf16 transposed [N][M]
__device__ __forceinline__ void mm_core(const u16* __restrict__ A, const u16* __restrict__ Wt,
                                        const float* __restrict__ bias, void* __restrict__ Cv,
                                        int M, int N, int K, int bm, int bn,
                                        u16* As, u16* Bs) {
  constexpr int MR = TM / 32;
  constexpr int AJ = TM / 32;
  int t = threadIdx.x;
  int wid = t >> 6, lane = t & 63;
  int wr = (wid >> 1) * (TM / 2), wc = (wid & 1) * 64;
  int lr = lane & 15, lg = lane >> 4;
  f32x4 acc[MR][4];
  f32x4 zf = {0.f, 0.f, 0.f, 0.f};
#pragma unroll
  for (int m = 0; m < MR; m++)
#pragma unroll
    for (int n = 0; n < 4; n++) acc[m][n] = zf;

  int srow = wid * 8 + (lane >> 3);
  int sgr = (lane & 7) ^ (lane >> 3);
  const u16* aSrc = A + (size_t)(bm + srow) * K + sgr * 8;
  const u16* bSrc = Wt + (size_t)(bn + srow) * K + sgr * 8;
  int dstOff = wid * 8 * 64;

  for (int kt = 0; kt < K; kt += 64) {
    __syncthreads();
#pragma unroll
    for (int j = 0; j < AJ; j++)
      gload16(aSrc + kt + (size_t)j * 32 * K, As + dstOff + j * 32 * 64);
#pragma unroll
    for (int j = 0; j < 4; j++)
      gload16(bSrc + kt + (size_t)j * 32 * K, Bs + dstOff + j * 32 * 64);
    __syncthreads();
#pragma unroll
    for (int ks = 0; ks < 2; ks++) {
      bf16x8 af[MR], bfr[4];
#pragma unroll
      for (int m = 0; m < MR; m++)
        af[m] = *(const bf16x8*)&As[(wr + m * 16 + lr) * 64 + (((ks * 4 + lg) ^ (lr & 7)) * 8)];
#pragma unroll
      for (int n = 0; n < 4; n++)
        bfr[n] = *(const bf16x8*)&Bs[(wc + n * 16 + lr) * 64 + (((ks * 4 + lg) ^ (lr & 7)) * 8)];
#pragma unroll
      for (int m = 0; m < MR; m++)
#pragma unroll
        for (int n = 0; n < 4; n++)
          acc[m][n] = __builtin_amdgcn_mfma_f32_16x16x32_bf16(af[m], bfr[n], acc[m][n], 0, 0, 0);
    }
  }
#pragma unroll
  for (int n = 0; n < 4; n++) {
    int col = bn + wc + n * 16 + lr;
    float bb = bias[col];
#pragma unroll
    for (int m = 0; m < MR; m++) {
#pragma unroll
      for (int r = 0; r < 4; r++) {
        int row = bm + wr + m * 16 + lg * 4 + r;
        float xv = acc[m][n][r] + bb;
        if (ACT == 1) xv = 0.5f * xv * (1.0f + erff(xv * 0.70710678118654752f));
        if (OUTM == 0) ((float*)Cv)[(size_t)row * N + col] = xv;
        else if (OUTM == 1) ((u16*)Cv)[(size_t)row * N + col] = f2bf(xv);
        else ((u16*)Cv)[(size_t)col * M + row] = f2bf(xv);
      }
    }
  }
}

// XCD-aware bijective swizzle (nwg % 8 == 0): chunk of nwg/8 consecutive logical
// blocks per XCD; logical order is bx-major so each XCD's B-panels stay L2-resident.
template <int ACT, int OUTM, int TM>
__global__ __launch_bounds__(256) void mm_kernel(const u16* A, const u16* Wt, const float* bias,
                                                 void* Cv, int M, int N, int K) {
  __shared__ u16 As[TM * 64];
  __shared__ u16 Bs[128 * 64];
  int nwg = gridDim.x * gridDim.y;
  int lin = blockIdx.y * gridDim.x + blockIdx.x;
  int swz = (lin & 7) * (nwg >> 3) + (lin >> 3);
  int bx = swz / gridDim.y, by = swz % gridDim.y;
  mm_core<ACT, OUTM, TM>(A, Wt, bias, Cv, M, N, K, by * TM, bx * 128, As, Bs);
}

// fused q/k/v/kg/vg projections (+ qg projection on the extra x-slot).
// slots 2 (v) and 4 (vg) store transposed.
__global__ __launch_bounds__(256) void mm5_kernel(
    const u16* A,
    const u16* W0, const u16* W1_, const u16* W2_, const u16* W3, const u16* W4,
    const float* b0, const float* b1, const float* b2, const float* b3, const float* b4,
    u16* C0, u16* C1, u16* C2, u16* C3, u16* C4, int M, int K,
    const float* __restrict__ h, const float* __restrict__ Wqg,
    const float* __restrict__ bqg, float* __restrict__ qg) {
  __shared__ u16 As[128 * 64];
  __shared__ u16 Bs[128 * 64];
  if (blockIdx.x == 30) {        // qg projection: 24 used blocks (8 gi x 3 col-blocks)
    int b = blockIdx.y;
    if (b >= 24) return;
    int gi = b / 3, c0 = (b % 3) * 256;
    int tid = threadIdx.x;
    float* hs = (float*)As;
    const float* hrow = h + (size_t)gi * GSTRIDE * DMODEL;
    for (int i = tid; i < DMODEL; i += 256) hs[i] = hrow[i];
    __syncthreads();
    float a = bqg[c0 + tid];
    for (int k = 0; k < DMODEL; k++) a += hs[k] * Wqg[(size_t)k * DMODEL + c0 + tid];
    qg[gi * DMODEL + c0 + tid] = a;
    return;
  }
  // 960 GEMM blocks: XCD swizzle, bx-major logical order (~4 B-panels per XCD chunk)
  int lin = blockIdx.y * 30 + blockIdx.x;
  int swz = (lin & 7) * 120 + (lin >> 3);
  int bx = swz >> 5, by = swz & 31;
  int which = bx / 6;
  int bn = (bx % 6) * 128;
  const u16* Ws[5] = {W0, W1_, W2_, W3, W4};
  const float* bs[5] = {b0, b1, b2, b3, b4};
  u16* Cs[5] = {C0, C1, C2, C3, C4};
  if (which == 2 || which == 4)
    mm_core<0, 2, 128>(A, Ws[which], bs[which], Cs[which], M, DMODEL, K, by * 128, bn, As, Bs);
  else
    mm_core<0, 1, 128>(A, Ws[which], bs[which], Cs[which], M, DMODEL, K, by * 128, bn, As, Bs);
}

// ---------------- sliding-window flash attention body (MFMA, 128-query tiles) ------
// Softmax: defer-max (T13) + deferred l-partials: common path has NO shuffle trees
// (local col-max + __any gate; per-lane partial sums, one butterfly at the end).
__device__ __forceinline__ void sliding_body(
    int bid, u16* Ps,
    const u16* __restrict__ qb, const u16* __restrict__ kb,
    const u16* __restrict__ vt, const int* __restrict__ xmask,
    u16* __restrict__ ctx) {
  int hh = bid >> 5;
  int q0 = (bid & 31) * 128;
  int w = threadIdx.x >> 6, lane = threadIdx.x & 63;
  int lr = lane & 15, lg = lane >> 4;
  int rowb = q0 + w * 32;
  f32x4 zf = {0.f, 0.f, 0.f, 0.f};
  u16* Pw = Ps + w * 2048;

  bf16x8 qf[2][2];
#pragma unroll
  for (int mf = 0; mf < 2; mf++) {
    const u16* qptr = qb + (size_t)(rowb + mf * 16 + lr) * DMODEL + hh * DHEAD;
    qf[mf][0] = *(const bf16x8*)(qptr + lg * 8);
    qf[mf][1] = *(const bf16x8*)(qptr + 32 + lg * 8);
  }

  float m_run[2][4], l_run[2][4];   // m row-uniform; l per-lane partial
  f32x4 ctxa[2][4];
#pragma unroll
  for (int mf = 0; mf < 2; mf++)
#pragma unroll
    for (int r = 0; r < 4; r++) {
      m_run[mf][r] = -1e30f; l_run[mf][r] = 0.f; ctxa[mf][r] = zf;
    }

  // ---- global-key tile (8 keys; P cols 0..15 real, 16..31 zeroed for PV) ----
  {
    int krow = (lr < NGLOB) ? lr * GSTRIDE : 0;
    const u16* kp = kb + (size_t)krow * DMODEL + hh * DHEAD + lg * 8;
    bf16x8 kf0 = *(const bf16x8*)kp;
    bf16x8 kf1 = *(const bf16x8*)(kp + 32);
#pragma unroll
    for (int mf = 0; mf < 2; mf++) {
      f32x4 sa = __builtin_amdgcn_mfma_f32_16x16x32_bf16(qf[mf][0], kf0, zf, 0, 0, 0);
      sa = __builtin_amdgcn_mfma_f32_16x16x32_bf16(qf[mf][1], kf1, sa, 0, 0, 0);
      float p0[4], tmax[4];
#pragma unroll
      for (int r = 0; r < 4; r++) {
        float s = (lr < NGLOB) ? sa[r] * 0.125f : -1e30f;
        p0[r] = s; tmax[r] = s;
      }
#pragma unroll
      for (int o = 8; o; o >>= 1)
#pragma unroll
        for (int r = 0; r < 4; r++) tmax[r] = fmaxf(tmax[r], __shfl_xor(tmax[r], o));
#pragma unroll
      for (int r = 0; r < 4; r++) {
        m_run[mf][r] = tmax[r];           // finite: global keys always valid
        p0[r] = __expf(p0[r] - tmax[r]);  // masked lanes -> exp(-huge) = 0
        l_run[mf][r] = p0[r];             // per-lane partial (own column)
      }
#pragma unroll
      for (int r = 0; r < 4; r++) {
        int qi = mf * 16 + lg * 4 + r;
        Pw[qi * 64 + (((lr >> 3) ^ (qi & 7)) * 8) + (lr & 7)] = f2bf(p0[r]);
        int k2 = 16 + lr;
        Pw[qi * 64 + (((k2 >> 3) ^ (qi & 7)) * 8) + (k2 & 7)] = 0;
      }
    }
    bf16x8 pf0 = *(const bf16x8*)&Pw[lr * 64 + ((lg ^ (lr & 7)) * 8)];
    bf16x8 pf1 = *(const bf16x8*)&Pw[(16 + lr) * 64 + ((lg ^ (lr & 7)) * 8)];
#pragma unroll
    for (int c2 = 0; c2 < 4; c2++) {
      bf16x8 vg8 = {0, 0, 0, 0, 0, 0, 0, 0};
      if (lg == 0) {
        const u16* vrow = vt + (size_t)(hh * DHEAD + c2 * 16 + lr) * S_LEN;
#pragma unroll
        for (int j = 0; j < 8; j++) vg8[j] = (short)vrow[(size_t)j * GSTRIDE];
      }
      ctxa[0][c2] = __builtin_amdgcn_mfma_f32_16x16x32_bf16(pf0, vg8, ctxa[0][c2], 0, 0, 0);
      ctxa[1][c2] = __builtin_amdgcn_mfma_f32_16x16x32_bf16(pf1, vg8, ctxa[1][c2], 0, 0, 0);
    }
  }

  // ---- 10 band tiles of 64 keys, covering [q0-256, q0+383] ----
  for (int tt = 0; tt < 10; tt++) {
    int base = q0 - WIN + tt * 64;
    if (base + 63 < 0 || base >= S_LEN) continue;
    bf16x8 kf[4][2];
    int keyc[4]; bool vc[4];
#pragma unroll
    for (int c = 0; c < 4; c++) {
      int key = base + c * 16 + lr;
      int krow = key < 0 ? 0 : (key > S_LEN - 1 ? S_LEN - 1 : key);
      vc[c] = (key >= 0) && (key < S_LEN) && ((key & (GSTRIDE - 1)) != 0) && (xmask[krow] != 0);
      keyc[c] = key;
      const u16* kp = kb + (size_t)krow * DMODEL + hh * DHEAD + lg * 8;
      kf[c][0] = *(const bf16x8*)kp;
      kf[c][1] = *(const bf16x8*)(kp + 32);
    }
#pragma unroll
    for (int mf = 0; mf < 2; mf++) {
      f32x4 sa[4];
#pragma unroll
      for (int c = 0; c < 4; c++) {
        sa[c] = __builtin_amdgcn_mfma_f32_16x16x32_bf16(qf[mf][0], kf[c][0], zf, 0, 0, 0);
        sa[c] = __builtin_amdgcn_mfma_f32_16x16x32_bf16(qf[mf][1], kf[c][1], sa[c], 0, 0, 0);
      }
      float p[4][4], lmax[4] = {-1e30f, -1e30f, -1e30f, -1e30f};
#pragma unroll
      for (int c = 0; c < 4; c++)
#pragma unroll
        for (int r = 0; r < 4; r++) {
          int qrow = rowb + mf * 16 + lg * 4 + r;
          int dd = keyc[c] - qrow;
          float s = (vc[c] && dd >= -WIN && dd <= WIN) ? sa[c][r] * 0.125f : -1e30f;
          p[c][r] = s;
          lmax[r] = fmaxf(lmax[r], s);
        }
      // defer-max gate: no shuffle tree unless some lane exceeds m_run+8
      float need = 0.f;
#pragma unroll
      for (int r = 0; r < 4; r++) need = fmaxf(need, lmax[r] - m_run[mf][r]);
      if (__any(need > 8.f)) {
        float tmax[4];
#pragma unroll
        for (int r = 0; r < 4; r++) tmax[r] = lmax[r];
#pragma unroll
        for (int o = 8; o; o >>= 1)
#pragma unroll
          for (int r = 0; r < 4; r++) tmax[r] = fmaxf(tmax[r], __shfl_xor(tmax[r], o));
        float sc[4];
#pragma unroll
        for (int r = 0; r < 4; r++) {
          float mn = fmaxf(m_run[mf][r], tmax[r]);
          sc[r] = __expf(m_run[mf][r] - mn);
          m_run[mf][r] = mn;
          l_run[mf][r] *= sc[r];
        }
#pragma unroll
        for (int c2 = 0; c2 < 4; c2++)
#pragma unroll
          for (int r = 0; r < 4; r++) ctxa[mf][c2][r] *= sc[r];
      }
#pragma unroll
      for (int c = 0; c < 4; c++)
#pragma unroll
        for (int r = 0; r < 4; r++) {
          p[c][r] = __expf(p[c][r] - m_run[mf][r]);  // masked -> exp(-huge)=0 (m finite)
          l_run[mf][r] += p[c][r];
        }
#pragma unroll
      for (int c = 0; c < 4; c++)
#pragma unroll
        for (int r = 0; r < 4; r++) {
          int qi = mf * 16 + lg * 4 + r, k64 = c * 16 + lr;
          Pw[qi * 64 + (((k64 >> 3) ^ (qi & 7)) * 8) + (k64 & 7)] = f2bf(p[c][r]);
        }
    }
#pragma unroll
    for (int ks = 0; ks < 2; ks++) {
      bf16x8 pf0 = *(const bf16x8*)&Pw[lr * 64 + (((ks * 4 + lg) ^ (lr & 7)) * 8)];
      bf16x8 pf1 = *(const bf16x8*)&Pw[(16 + lr) * 64 + (((ks * 4 + lg) ^ (lr & 7)) * 8)];
      int kstart = base + ks * 32 + lg * 8;
      int kc = kstart < 0 ? 0 : (kstart > S_LEN - 8 ? S_LEN - 8 : kstart);
#pragma unroll
      for (int c2 = 0; c2 < 4; c2++) {
        const u16* vp = vt + (size_t)(hh * DHEAD + c2 * 16 + lr) * S_LEN + kc;
        bf16x8 vf = *(const bf16x8*)vp;
        ctxa[0][c2] = __builtin_amdgcn_mfma_f32_16x16x32_bf16(pf0, vf, ctxa[0][c2], 0, 0, 0);
        ctxa[1][c2] = __builtin_amdgcn_mfma_f32_16x16x32_bf16(pf1, vf, ctxa[1][c2], 0, 0, 0);
      }
    }
  }

  // finalize l: one butterfly over the 16-lane row group
#pragma unroll
  for (int mf = 0; mf < 2; mf++)
#pragma unroll
    for (int o = 8; o; o >>= 1)
#pragma unroll
      for (int r = 0; r < 4; r++) l_run[mf][r] += __shfl_xor(l_run[mf][r], o);

  // store (skip gpos rows — owned by the gattn blocks in this same dispatch)
#pragma unroll
  for (int mf = 0; mf < 2; mf++)
#pragma unroll
    for (int c2 = 0; c2 < 4; c2++)
#pragma unroll
      for (int r = 0; r < 4; r++) {
        int qrow = rowb + mf * 16 + lg * 4 + r;
        if ((qrow & (GSTRIDE - 1)) != 0)
          ctx[(size_t)qrow * DMODEL + hh * DHEAD + c2 * 16 + lr] = f2bf(ctxa[mf][c2][r] / l_run[mf][r]);
      }
}

// ---------------- single-pass global-token attention (one block per head) ---------
__device__ __forceinline__ void gattn_body(
    int hh, u16* Ps, float* cM, float* cL, float* cA,
    const float* __restrict__ qg, const u16* __restrict__ kg,
    const u16* __restrict__ vgt, const int* __restrict__ xmask,
    u16* __restrict__ ctx) {
  int w = threadIdx.x >> 6, lane = threadIdx.x & 63;
  int lr = lane & 15, lg = lane >> 4;
  f32x4 zf = {0.f, 0.f, 0.f, 0.f};
  u16* Pw = Ps + w * 1024;

  bf16x8 qf0, qf1;
  {
    const float* qp = qg + (size_t)(lr & 7) * DMODEL + hh * DHEAD;
    bool real = lr < 8;
#pragma unroll
    for (int j = 0; j < 8; j++) {
      qf0[j] = real ? (short)f2bf(0.125f * qp[lg * 8 + j]) : (short)0;
      qf1[j] = real ? (short)f2bf(0.125f * qp[32 + lg * 8 + j]) : (short)0;
    }
  }

  float m_run[4] = {-1e30f, -1e30f, -1e30f, -1e30f};
  float l_run[4] = {0.f, 0.f, 0.f, 0.f};    // per-lane partial
  f32x4 ctxa[4] = {zf, zf, zf, zf};

  for (int tt = w; tt < 64; tt += 4) {
    int base = tt * 64;
    f32x4 sa[4];
    bool vc[4];
#pragma unroll
    for (int st = 0; st < 4; st++) {
      int key = base + st * 16 + lr;
      vc[st] = (xmask[key] != 0) || ((key & (GSTRIDE - 1)) == 0);
      const u16* kp = kg + (size_t)key * DMODEL + hh * DHEAD + lg * 8;
      sa[st] = __builtin_amdgcn_mfma_f32_16x16x32_bf16(qf0, *(const bf16x8*)kp, zf, 0, 0, 0);
      sa[st] = __builtin_amdgcn_mfma_f32_16x16x32_bf16(qf1, *(const bf16x8*)(kp + 32), sa[st], 0, 0, 0);
    }
    float p[4][4], lmax[4] = {-1e30f, -1e30f, -1e30f, -1e30f};
#pragma unroll
    for (int st = 0; st < 4; st++)
#pragma unroll
      for (int r = 0; r < 4; r++) {
        float s = vc[st] ? sa[st][r] : -1e30f;
        p[st][r] = s;
        lmax[r] = fmaxf(lmax[r], s);
      }
    float need = 0.f;
#pragma unroll
    for (int r = 0; r < 4; r++) need = fmaxf(need, lmax[r] - m_run[r]);
    if (__any(need > 8.f)) {
      float tmax[4];
#pragma unroll
      for (int r = 0; r < 4; r++) tmax[r] = lmax[r];
#pragma unroll
      for (int o = 8; o; o >>= 1)
#pragma unroll
        for (int r = 0; r < 4; r++) tmax[r] = fmaxf(tmax[r], __shfl_xor(tmax[r], o));
      float sc[4];
#pragma unroll
      for (int r = 0; r < 4; r++) {
        float mn = fmaxf(m_run[r], tmax[r]);
        sc[r] = __expf(m_run[r] - mn);
        m_run[r] = mn;
        l_run[r] *= sc[r];
      }
#pragma unroll
      for (int c2 = 0; c2 < 4; c2++)
#pragma unroll
        for (int r = 0; r < 4; r++) ctxa[c2][r] *= sc[r];
    }
#pragma unroll
    for (int st = 0; st < 4; st++)
#pragma unroll
      for (int r = 0; r < 4; r++) {
        float pv = vc[st] ? __expf(p[st][r] - m_run[r]) : 0.f;  // guard: m may be -1e30
        p[st][r] = pv;
        l_run[r] += pv;
      }
#pragma unroll
    for (int st = 0; st < 4; st++)
#pragma unroll
      for (int r = 0; r < 4; r++) {
        int qi = lg * 4 + r, k64 = st * 16 + lr;
        Pw[qi * 64 + (((k64 >> 3) ^ (qi & 7)) * 8) + (k64 & 7)] = f2bf(p[st][r]);
      }
#pragma unroll
    for (int ks = 0; ks < 2; ks++) {
      bf16x8 pf = *(const bf16x8*)&Pw[lr * 64 + (((ks * 4 + lg) ^ (lr & 7)) * 8)];
      int kstart = base + ks * 32 + lg * 8;
#pragma unroll
      for (int c2 = 0; c2 < 4; c2++) {
        const u16* vp = vgt + (size_t)(hh * DHEAD + c2 * 16 + lr) * S_LEN + kstart;
        ctxa[c2] = __builtin_amdgcn_mfma_f32_16x16x32_bf16(pf, *(const bf16x8*)vp, ctxa[c2], 0, 0, 0);
      }
    }
  }

  // finalize per-wave l (butterfly), then write partials for 4-way combine
#pragma unroll
  for (int o = 8; o; o >>= 1)
#pragma unroll
    for (int r = 0; r < 4; r++) l_run[r] += __shfl_xor(l_run[r], o);

  if (lg < 2) {
#pragma unroll
    for (int r = 0; r < 4; r++) {
      int q = lg * 4 + r;
#pragma unroll
      for (int c2 = 0; c2 < 4; c2++)
        cA[(w * 8 + q) * 64 + c2 * 16 + lr] = ctxa[c2][r];
      if (lr == 0) {
        cM[w * 8 + q] = m_run[r];
        cL[w * 8 + q] = l_run[r];
      }
    }
  }
  __syncthreads();
  int t = threadIdx.x;
#pragma unroll
  for (int half = 0; half < 2; half++) {
    int slot = half * 256 + t;      // q*64 + d
    int q = slot >> 6, d = slot & 63;
    float M = fmaxf(fmaxf(cM[q], cM[8 + q]), fmaxf(cM[16 + q], cM[24 + q]));
    float L = 0.f, A = 0.f;
#pragma unroll
    for (int ww = 0; ww < 4; ww++) {
      float al = __expf(cM[ww * 8 + q] - M);
      L += cL[ww * 8 + q] * al;
      A += cA[(ww * 8 + q) * 64 + d] * al;
    }
    ctx[(size_t)q * GSTRIDE * DMODEL + hh * DHEAD + d] = f2bf(A / L);
  }
}

// ---------------- merged attention dispatch: gattn (12) + sliding (384) ----------
__global__ __launch_bounds__(256) void attn_kernel(
    const u16* __restrict__ qb, const u16* __restrict__ kb,
    const u16* __restrict__ vt, const int* __restrict__ xmask,
    u16* __restrict__ ctx,
    const float* __restrict__ qg, const u16* __restrict__ kg,
    const u16* __restrict__ vgt) {
  __shared__ u16 Ps[4 * 32 * 64];
  __shared__ float cM[32], cL[32], cA[32 * 64];
  int bid = blockIdx.x;
  if (bid < NHEAD) {
    gattn_body(bid, Ps, cM, cL, cA, qg, kg, vgt, xmask, ctx);
  } else {
    sliding_body(bid - NHEAD, Ps, qb, kb, vt, xmask, ctx);
  }
}

// ---------------- CLS pooling + output projection -----------------
__global__ __launch_bounds__(128) void cls_out_kernel(
    const float* __restrict__ h, const float* __restrict__ ow,
    const float* __restrict__ ob, float* __restrict__ y) {
  __shared__ float hs[DMODEL];
  int wi = blockIdx.x;
  int tid = threadIdx.x;
  for (int i = tid; i < DMODEL; i += 128) hs[i] = h[(size_t)wi * GSTRIDE * DMODEL + i];
  __syncthreads();
  float a = ob[tid];
  for (int d = 0; d < DMODEL; d++) a += hs[d] * ow[d * 128 + tid];
  y[wi * 128 + tid] = a;
}

// ---------------- host launch ----------------
extern "C" void kernel_launch(void* const* d_in, const int* in_sizes, int n_in,
                              void* d_out, int out_size, void* d_ws, size_t ws_size,
                              hipStream_t stream) {
  const int*   x      = (const int*)d_in[0];
  const int*   xmask  = (const int*)d_in[1];
  const float* wemb   = (const float*)d_in[2];
  const float* pemb   = (const float*)d_in[3];
  const float* emb_g  = (const float*)d_in[4];
  const float* emb_b  = (const float*)d_in[5];
  const float* Wq     = (const float*)d_in[6];
  const float* bq     = (const float*)d_in[7];
  const float* Wk     = (const float*)d_in[8];
  const float* bk     = (const float*)d_in[9];
  const float* Wv     = (const float*)d_in[10];
  const float* bv     = (const float*)d_in[11];
  const float* Wo     = (const float*)d_in[12];
  const float* bo     = (const float*)d_in[13];
  const float* Wqg    = (const float*)d_in[14];
  const float* bqg    = (const float*)d_in[15];
  const float* Wkg    = (const float*)d_in[16];
  const float* bkg    = (const float*)d_in[17];
  const float* Wvg    = (const float*)d_in[18];
  const float* bvg    = (const float*)d_in[19];
  const float* ln1_g  = (const float*)d_in[20];
  const float* ln1_b  = (const float*)d_in[21];
  const float* W1     = (const float*)d_in[22];
  const float* b1     = (const float*)d_in[23];
  const float* W2     = (const float*)d_in[24];
  const float* b2     = (const float*)d_in[25];
  const float* ln2_g  = (const float*)d_in[26];
  const float* ln2_b  = (const float*)d_in[27];
  const float* out_w  = (const float*)d_in[28];
  const float* out_b  = (const float*)d_in[29];

  char* wsp = (char*)d_ws;
  float* h   = (float*)wsp;  wsp += (size_t)S_LEN * DMODEL * 4;
  u16* tmpb  = (u16*)wsp;    wsp += (size_t)S_LEN * DMODEL * 2;
  u16* hb  = (u16*)wsp;      wsp += (size_t)S_LEN * DMODEL * 2;
  u16* ctx = (u16*)wsp;      wsp += (size_t)S_LEN * DMODEL * 2;
  u16* qb  = (u16*)wsp;      wsp += (size_t)S_LEN * DMODEL * 2;
  u16* kb  = (u16*)wsp;      wsp += (size_t)S_LEN * DMODEL * 2;
  u16* vt  = (u16*)wsp;      wsp += (size_t)S_LEN * DMODEL * 2;
  u16* kgb = (u16*)wsp;      wsp += (size_t)S_LEN * DMODEL * 2;
  u16* vgt = (u16*)wsp;      wsp += (size_t)S_LEN * DMODEL * 2;
  u16* mid = (u16*)wsp;      wsp += (size_t)S_LEN * FDIM * 2;
  float* qgb = (float*)wsp;  wsp += (size_t)NGLOB * DMODEL * 4;
  u16* wtb = (u16*)wsp;      wsp += WSTRIDE * NLAYER * 2;

  embed_ln_kernel<<<S_LEN, 256, 0, stream>>>(x, wemb, pemb, emb_g, emb_b, h, hb);
  convw_kernel<<<dim3(2016, NLAYER), 256, 0, stream>>>(Wq, Wk, Wv, Wkg, Wvg, Wo, W1, W2, wtb);

  for (int l = 0; l < NLAYER; l++) {
    const float* bql  = bq  + (size_t)l * DMODEL;
    const float* bkl  = bk  + (size_t)l * DMODEL;
    const float* bvl  = bv  + (size_t)l * DMODEL;
    const float* bol  = bo  + (size_t)l * DMODEL;
    const float* wqg  = Wqg + (size_t)l * DD_;
    const float* bqgl = bqg + (size_t)l * DMODEL;
    const float* bkgl = bkg + (size_t)l * DMODEL;
    const float* bvgl = bvg + (size_t)l * DMODEL;
    const float* b1l  = b1  + (size_t)l * FDIM;
    const float* b2l  = b2  + (size_t)l * DMODEL;
    u16* base = wtb + (size_t)l * WSTRIDE;
    u16* wqT  = base;
    u16* wkT  = base + 1 * DD_;
    u16* wvT  = base + 2 * DD_;
    u16* wkgT = base + 3 * DD_;
    u16* wvgT = base + 4 * DD_;
    u16* woT  = base + 5 * DD_;
    u16* w1T  = base + 6 * DD_;
    u16* w2T  = base + 6 * DD_ + DF_;

    mm5_kernel<<<dim3(31, 32), 256, 0, stream>>>(
        hb, wqT, wkT, wvT, wkgT, wvgT, bql, bkl, bvl, bkgl, bvgl,
        qb, kb, vt, kgb, vgt, S_LEN, DMODEL, h, wqg, bqgl, qgb);

    attn_kernel<<<NHEAD + NHEAD * 32, 256, 0, stream>>>(
        qb, kb, vt, xmask, ctx, qgb, kgb, vgt);

    mm_kernel<0, 1, 64><<<dim3(6, 64), 256, 0, stream>>>(ctx, woT, bol, tmpb, S_LEN, DMODEL, DMODEL);
    add_ln_kernel<<<S_LEN, 256, 0, stream>>>(h, tmpb, ln1_g + (size_t)l * DMODEL,
                                             ln1_b + (size_t)l * DMODEL, hb);

    mm_kernel<1, 1, 128><<<dim3(24, 32), 256, 0, stream>>>(hb, w1T, b1l, mid, S_LEN, FDIM, DMODEL);
    mm_kernel<0, 1, 64><<<dim3(6, 64), 256, 0, stream>>>(mid, w2T, b2l, tmpb, S_LEN, DMODEL, FDIM);
    add_ln_kernel<<<S_LEN, 256, 0, stream>>>(h, tmpb, ln2_g + (size_t)l * DMODEL,
                                             ln2_b + (size_t)l * DMODEL, hb);
  }

  cls_out_kernel<<<NGLOB, 128, 0, stream>>>(h, out_w, out_b, (float*)d_out);
}